// Round 12
// baseline (409.929 us; speedup 1.0000x reference)
//
#include <hip/hip_runtime.h>
#include <hip/hip_fp16.h>
#include <math.h>
#include <stdint.h>

#define DD 128
#define BSH 9            // bucket shift: 512 rows per bucket

typedef _Float16 f16;
typedef _Float16 f16x2 __attribute__((ext_vector_type(2)));
typedef _Float16 f16x8 __attribute__((ext_vector_type(8)));
typedef float f32x4 __attribute__((ext_vector_type(4)));

// ================= merged: weight prep (blocks 0..5) + edge histogram (blocks 6..) =================
__global__ __launch_bounds__(256) void k_ph(
    const float* __restrict__ w0, const float* __restrict__ w1, const float* __restrict__ w2,
    const float* __restrict__ w3, const float* __restrict__ w4, const float* __restrict__ w5,
    f16* __restrict__ wh,
    const int* __restrict__ r1, const int* __restrict__ r2, int* __restrict__ hist,
    int E, int tile, int nt){
  __shared__ __align__(16) unsigned char smem[128*136*2];
  int t = threadIdx.x;
  if((int)blockIdx.x < 6){
    auto tw = (f16 (*)[136])smem;
    int b = blockIdx.x;
    const float* W = (b==0)?w0:(b==1)?w1:(b==2)?w2:(b==3)?w3:(b==4)?w4:w5;
    for(int j=0;j<16;++j){
      int f = j*256+t; int k = f>>5, c4 = f&31;
      float4 v = *(const float4*)(W + (size_t)k*DD + c4*4);
      tw[c4*4+0][k]=(f16)v.x; tw[c4*4+1][k]=(f16)v.y; tw[c4*4+2][k]=(f16)v.z; tw[c4*4+3][k]=(f16)v.w;
    }
    __syncthreads();
    f16* dst = wh + (size_t)b*16384;
    for(int j=0;j<8;++j){
      int f = j*256+t; int c = f>>4, seg = f&15;
      *(int4*)&dst[(size_t)c*DD + seg*8] = *(int4*)&tw[c][seg*8];
    }
  } else {
    int* h1 = (int*)smem; int* h2 = h1+256;
    h1[t]=0; h2[t]=0; __syncthreads();
    int hb = blockIdx.x - 6;
    int e0 = hb*tile, e1 = min(e0+tile, E);
    for(int e=e0+t; e<e1; e+=256){
      atomicAdd(&h1[r1[e]>>BSH], 1);
      atomicAdd(&h2[r2[e]>>BSH], 1);
    }
    __syncthreads();
    hist[(size_t)hb*256 + t] = h1[t];
    hist[(size_t)nt*256 + (size_t)hb*256 + t] = h2[t];
  }
}

__global__ void k_colscan(int* __restrict__ hist, int* __restrict__ colsum, int nt){
  __shared__ int sh[256];
  int g = blockIdx.x>>8, b = blockIdx.x&255;
  int t = threadIdx.x;
  int* H = hist + (size_t)g*nt*256;
  int v = (t<nt)? H[(size_t)t*256+b] : 0;
  sh[t]=v; __syncthreads();
  for(int off=1; off<256; off<<=1){
    int add = (t>=off)? sh[t-off] : 0;
    __syncthreads(); sh[t]+=add; __syncthreads();
  }
  if(t<nt) H[(size_t)t*256+b] = sh[t]-v;
  if(t==255) colsum[g*256+b] = sh[255];
}

__global__ void k_basescan(const int* __restrict__ colsum, int* __restrict__ base){
  __shared__ int sh[512];
  int t = threadIdx.x;
  int g = t>>8, st = t&255;
  int v = colsum[t];
  sh[t]=v; __syncthreads();
  for(int off=1; off<256; off<<=1){
    int add = (st>=off)? sh[t-off] : 0;
    __syncthreads(); sh[t]+=add; __syncthreads();
  }
  base[g*257+st] = sh[t]-v;
  if(st==255) base[g*257+256] = sh[t];
}

// ================= merged: partition (blocks 0..nt-1) + x-GEMMs (blocks nt..) =================
__global__ __launch_bounds__(256) void k_px(
    const int* __restrict__ r1, const int* __restrict__ c1, const float* __restrict__ v1,
    const int* __restrict__ r2, const int* __restrict__ c2,
    const int* __restrict__ hist, const int* __restrict__ base,
    int2* __restrict__ st1, int* __restrict__ st2, int E, int tile, int nt,
    const float* __restrict__ x, const f16* __restrict__ wh,
    f16* __restrict__ h1h, f16* __restrict__ mapped,
    float* __restrict__ s1, float* __restrict__ s2,
    float bn, float sscale, int n){
  __shared__ __align__(16) unsigned char smem[52224];
  int t = threadIdx.x;
  if((int)blockIdx.x < nt){
    int* l1 = (int*)smem; int* l2 = l1+256;
    l1[t]=0; l2[t]=0; __syncthreads();
    int bx = blockIdx.x;
    int e0 = bx*tile, e1e = min(e0+tile, E);
    const int* off1 = hist + (size_t)bx*256;
    const int* off2 = hist + (size_t)nt*256 + (size_t)bx*256;
    for(int e=e0+t; e<e1e; e+=256){
      {
        int r = r1[e]; int b = r>>BSH;
        int rank = atomicAdd(&l1[b], 1);
        int dst = base[b] + off1[b] + rank;
        st1[dst] = make_int2(((r - (b<<BSH))<<17) | c1[e], __float_as_int(v1[e]));
      }
      {
        int r = r2[e]; int b = r>>BSH;
        int rank = atomicAdd(&l2[b], 1);
        int dst = base[257+b] + off2[b] + rank;
        st2[dst] = ((r - (b<<BSH))<<17) | c2[e];
      }
    }
  } else {
    auto at = (f16 (*)[136])smem;
    auto wt = (f16 (*)[136])(smem + 64*136*2);
    int r0 = (blockIdx.x - nt)*64;
    int l = t&63, w = t>>6, li = l&15, g = l>>4;
    for(int p=0;p<4;++p){
      int row = p*16 + (t>>4), seg = t&15;
      union{ f16 h[8]; int4 v; } u;
      u.v = make_int4(0,0,0,0);
      if(r0+row < n){
        const float* src = x + (size_t)(r0+row)*DD + seg*8;
        float4 a = *(const float4*)src, b = *(const float4*)(src+4);
        u.h[0]=(f16)a.x; u.h[1]=(f16)a.y; u.h[2]=(f16)a.z; u.h[3]=(f16)a.w;
        u.h[4]=(f16)b.x; u.h[5]=(f16)b.y; u.h[6]=(f16)b.z; u.h[7]=(f16)b.w;
      }
      *(int4*)&at[row][seg*8] = u.v;
    }
    for(int p=0;p<4;++p){
      __syncthreads();
      const f16* Wp = wh + (size_t)p*16384;
      for(int j=0;j<8;++j){
        int f = j*256+t; int c = f>>4, seg = f&15;
        *(int4*)&wt[c][seg*8] = *(const int4*)(Wp + (size_t)c*DD + seg*8);
      }
      __syncthreads();
      f32x4 acc[8];
      #pragma unroll
      for(int ct=0;ct<8;++ct) acc[ct] = (f32x4){0.f,0.f,0.f,0.f};
      #pragma unroll
      for(int ks=0;ks<4;++ks){
        f16x8 a = *(const f16x8*)&at[w*16+li][ks*32+g*8];
        #pragma unroll
        for(int ct=0;ct<8;++ct){
          f16x8 b = *(const f16x8*)&wt[ct*16+li][ks*32+g*8];
          acc[ct] = __builtin_amdgcn_mfma_f32_16x16x32_f16(a, b, acc[ct], 0,0,0);
        }
      }
      if(p<2){
        f16* out = p ? mapped : h1h;
        __syncthreads();
        #pragma unroll
        for(int ct=0;ct<8;++ct)
          #pragma unroll
          for(int reg=0;reg<4;++reg)
            wt[w*16+g*4+reg][ct*16+li] = (f16)(acc[ct][reg]*bn);
        __syncthreads();
        for(int j=0;j<4;++j){
          int f = j*256+t; int row = f>>4, seg = f&15;
          if(r0+row < n) *(int4*)&out[(size_t)(r0+row)*DD + seg*8] = *(int4*)&wt[row][seg*8];
        }
      } else {
        float* sd = (p==2) ? s1 : s2;
        #pragma unroll
        for(int reg=0;reg<4;++reg){
          float pd = 0.f;
          #pragma unroll
          for(int ct=0;ct<8;++ct)
            pd += acc[ct][reg]*(float)at[w*16+g*4+reg][ct*16+li];
          pd += __shfl_xor(pd,1,64); pd += __shfl_xor(pd,2,64);
          pd += __shfl_xor(pd,4,64); pd += __shfl_xor(pd,8,64);
          if(li==0){
            int grow = r0 + w*16 + g*4 + reg;
            if(grow < n) sd[grow] = tanhf(sscale*pd);
          }
        }
      }
    }
  }
}

__global__ void k_csr_bucket(const int2* __restrict__ st1, const int* __restrict__ st2,
                             const int* __restrict__ base,
                             int2* __restrict__ e1, int* __restrict__ e2,
                             int* __restrict__ rs, int N, int nbk){
  __shared__ int cnt[512];
  __shared__ int cur[512];
  __shared__ int sc[256];
  int g = blockIdx.x / nbk;
  int b = blockIdx.x % nbk;
  int t = threadIdx.x;
  cnt[t]=0; cnt[256+t]=0;
  __syncthreads();
  int ebeg = base[g*257+b], eend = base[g*257+b+1];
  if(g==0){
    for(int i=ebeg+t; i<eend; i+=256) atomicAdd(&cnt[st1[i].x>>17], 1);
  } else {
    for(int i=ebeg+t; i<eend; i+=256) atomicAdd(&cnt[st2[i]>>17], 1);
  }
  __syncthreads();
  int a0 = cnt[2*t], a1 = cnt[2*t+1];
  int s = a0+a1;
  sc[t]=s; __syncthreads();
  for(int off=1; off<256; off<<=1){
    int add = (t>=off)? sc[t-off] : 0;
    __syncthreads(); sc[t]+=add; __syncthreads();
  }
  int ex = sc[t]-s;
  cur[2*t] = ex; cur[2*t+1] = ex + a0;
  __syncthreads();
  int r0 = b<<BSH;
  int* rsg = rs + (size_t)g*(N+1);
  for(int i=t; i<512; i+=256){
    int r = r0+i;
    if(r<N) rsg[r] = ebeg + cur[i];
  }
  if(b==nbk-1 && t==0) rsg[N] = base[g*257+256];
  __syncthreads();
  if(g==0){
    for(int i=ebeg+t; i<eend; i+=256){
      int2 w = st1[i];
      int lr = w.x>>17;
      int p = ebeg + atomicAdd(&cur[lr], 1);
      e1[p] = make_int2(w.x & 0x1FFFF, w.y);
    }
  } else {
    for(int i=ebeg+t; i<eend; i+=256){
      int w = st2[i];
      int lr = w>>17;
      int p = ebeg + atomicAdd(&cur[lr], 1);
      e2[p] = w & 0x1FFFF;
    }
  }
}

// ================= highway GEMM + gcn2 GEMM fused (y2h -> y3h -> h3h) =================
__global__ __launch_bounds__(256) void k_hw2(
    const f16* __restrict__ y2h, const f16* __restrict__ y1h,
    const f16* __restrict__ wh, f16* __restrict__ y3h, f16* __restrict__ h3h,
    float bn, int n){
  __shared__ __align__(16) f16 at[64][136];
  __shared__ __align__(16) f16 wt[128][136];
  int t = threadIdx.x;
  int r0 = blockIdx.x*64;
  int l = t&63, w = t>>6, li = l&15, g = l>>4;
  for(int p=0;p<4;++p){
    int row = p*16 + (t>>4), seg = t&15;
    int4 v = make_int4(0,0,0,0);
    if(r0+row < n) v = *(const int4*)(y2h + (size_t)(r0+row)*DD + seg*8);
    *(int4*)&at[row][seg*8] = v;
  }
  __syncthreads();
  for(int j=0;j<8;++j){
    int f = j*256+t; int c = f>>4, seg = f&15;
    *(int4*)&wt[c][seg*8] = *(const int4*)(wh + (size_t)4*16384 + (size_t)c*DD + seg*8);
  }
  __syncthreads();
  f32x4 acc[8];
  #pragma unroll
  for(int ct=0;ct<8;++ct) acc[ct] = (f32x4){0.f,0.f,0.f,0.f};
  #pragma unroll
  for(int ks=0;ks<4;++ks){
    f16x8 a = *(const f16x8*)&at[w*16+li][ks*32+g*8];
    #pragma unroll
    for(int ct=0;ct<8;++ct){
      f16x8 b = *(const f16x8*)&wt[ct*16+li][ks*32+g*8];
      acc[ct] = __builtin_amdgcn_mfma_f32_16x16x32_f16(a, b, acc[ct], 0,0,0);
    }
  }
  float res[8][4];
  #pragma unroll
  for(int ct=0;ct<8;++ct)
    #pragma unroll
    for(int reg=0;reg<4;++reg){
      int lrow = w*16+g*4+reg, col = ct*16+li;
      int grow = r0+lrow;
      float gt = tanhf(bn*acc[ct][reg]); gt = fmaxf(gt, 0.f);
      float y1v = (grow<n)? (float)y1h[(size_t)grow*DD+col] : 0.f;
      float y2v = (float)at[lrow][col];
      res[ct][reg] = tanhf(bn*(y1v*(1.f-gt) + y2v*gt));
    }
  #pragma unroll
  for(int ct=0;ct<8;++ct)
    #pragma unroll
    for(int reg=0;reg<4;++reg)
      at[w*16+g*4+reg][ct*16+li] = (f16)res[ct][reg];
  __syncthreads();
  for(int j=0;j<4;++j){
    int f = j*256+t; int row = f>>4, seg = f&15;
    if(r0+row < n) *(int4*)&y3h[(size_t)(r0+row)*DD + seg*8] = *(int4*)&at[row][seg*8];
  }
  __syncthreads();
  for(int j=0;j<8;++j){
    int f = j*256+t; int c = f>>4, seg = f&15;
    *(int4*)&wt[c][seg*8] = *(const int4*)(wh + (size_t)5*16384 + (size_t)c*DD + seg*8);
  }
  __syncthreads();
  #pragma unroll
  for(int ct=0;ct<8;++ct) acc[ct] = (f32x4){0.f,0.f,0.f,0.f};
  #pragma unroll
  for(int ks=0;ks<4;++ks){
    f16x8 a = *(const f16x8*)&at[w*16+li][ks*32+g*8];
    #pragma unroll
    for(int ct=0;ct<8;++ct){
      f16x8 b = *(const f16x8*)&wt[ct*16+li][ks*32+g*8];
      acc[ct] = __builtin_amdgcn_mfma_f32_16x16x32_f16(a, b, acc[ct], 0,0,0);
    }
  }
  __syncthreads();
  #pragma unroll
  for(int ct=0;ct<8;++ct)
    #pragma unroll
    for(int reg=0;reg<4;++reg)
      wt[w*16+g*4+reg][ct*16+li] = (f16)(acc[ct][reg]*bn);
  __syncthreads();
  for(int j=0;j<4;++j){
    int f = j*256+t; int row = f>>4, seg = f&15;
    if(r0+row < n) *(int4*)&h3h[(size_t)(r0+row)*DD + seg*8] = *(int4*)&wt[row][seg*8];
  }
}

// ================= 16-lane-row gather helpers (pk_fma accum, depth-2 software pipeline) =================
__device__ __forceinline__ void spmm_row16_h(const int* __restrict__ rs, const int2* __restrict__ e1,
                                             const __half* __restrict__ h, int row, int l,
                                             f16x2 acc2[4]){
  int beg = rs[row], end = rs[row+1];
  #pragma unroll
  for(int q=0;q<4;++q) acc2[q] = (f16x2){(f16)0.f,(f16)0.f};
  if(beg >= end) return;
  union U{ uint4 v; f16x2 h2[4]; };
  int2 cvA[8], cvB[8];
  U pA[8];
  #pragma unroll
  for(int j=0;j<8;++j) cvA[j] = e1[min(beg+j, end-1)];
  #pragma unroll
  for(int j=0;j<8;++j) pA[j].v = ((const uint4*)(h + (size_t)cvA[j].x*DD))[l];
  #pragma unroll
  for(int j=0;j<8;++j) cvB[j] = e1[min(beg+8+j, end-1)];
  for(int k=beg; k<end; k+=8){
    U pB[8];
    #pragma unroll
    for(int j=0;j<8;++j) pB[j].v = ((const uint4*)(h + (size_t)cvB[j].x*DD))[l];
    int2 cvN[8];
    #pragma unroll
    for(int j=0;j<8;++j) cvN[j] = e1[min(k+16+j, end-1)];
    #pragma unroll
    for(int j=0;j<8;++j){
      float v = (k+j<end)? __int_as_float(cvA[j].y) : 0.f;
      f16 vh = (f16)v;
      f16x2 vv = {vh, vh};
      #pragma unroll
      for(int q=0;q<4;++q) acc2[q] += pA[j].h2[q]*vv;
    }
    #pragma unroll
    for(int j=0;j<8;++j){ cvA[j]=cvB[j]; cvB[j]=cvN[j]; pA[j]=pB[j]; }
  }
}

__device__ __forceinline__ void attn_row16(const int* __restrict__ rs, const int* __restrict__ e2,
                                           const float* __restrict__ s1, const float* __restrict__ s2,
                                           const __half* __restrict__ mapped, __half* __restrict__ out,
                                           int row, int l){
  int beg = rs[row], end = rs[row+1];
  float s1r = s1[row];
  f16x2 a2[4];
  #pragma unroll
  for(int q=0;q<4;++q) a2[q] = (f16x2){(f16)0.f,(f16)0.f};
  float den = 0.f;
  if(end > beg){
    union U{ uint4 v; f16x2 h2[4]; };
    int csA[8], csB[8];
    float svA[8];
    U pA[8];
    #pragma unroll
    for(int j=0;j<8;++j) csA[j] = e2[min(beg+j, end-1)];
    #pragma unroll
    for(int j=0;j<8;++j) pA[j].v = ((const uint4*)(mapped + (size_t)csA[j]*DD))[l];
    #pragma unroll
    for(int j=0;j<8;++j) svA[j] = s2[csA[j]];
    #pragma unroll
    for(int j=0;j<8;++j) csB[j] = e2[min(beg+8+j, end-1)];
    for(int k=beg; k<end; k+=8){
      U pB[8];
      float svB[8];
      #pragma unroll
      for(int j=0;j<8;++j) pB[j].v = ((const uint4*)(mapped + (size_t)csB[j]*DD))[l];
      #pragma unroll
      for(int j=0;j<8;++j) svB[j] = s2[csB[j]];
      int csN[8];
      #pragma unroll
      for(int j=0;j<8;++j) csN[j] = e2[min(k+16+j, end-1)];
      #pragma unroll
      for(int j=0;j<8;++j){
        float e = s1r + svA[j]; e = (e>=0.f)? e : 0.2f*e;
        float ex = (k+j<end)? __expf(e) : 0.f;
        den += ex;
        f16 xh = (f16)ex;
        f16x2 xx = {xh, xh};
        #pragma unroll
        for(int q=0;q<4;++q) a2[q] += pB ? pA[j].h2[q]*xx : pA[j].h2[q]*xx;
      }
      #pragma unroll
      for(int j=0;j<8;++j){ csA[j]=csB[j]; csB[j]=csN[j]; svA[j]=svB[j]; pA[j]=pB[j]; }
    }
  }
  float inv = (end > beg) ? 1.0f/den : 0.0f;
  union{ uint4 v; __half2 h2[4]; } o;
  #pragma unroll
  for(int q=0;q<4;++q)
    o.h2[q] = __floats2half2_rn((float)a2[q].x*inv, (float)a2[q].y*inv);
  ((uint4*)(out + (size_t)row*DD))[l] = o.v;
}

// ================= merged aggregation 1: spmm(a1)->y1h AND attn->y2h (16 rows/block) =================
__global__ void k_agg1(const int* __restrict__ rs, const int2* __restrict__ e1,
                       const __half* __restrict__ h1h, const float* __restrict__ b1, __half* __restrict__ y1h,
                       const int* __restrict__ e2, const float* __restrict__ s1, const float* __restrict__ s2,
                       const __half* __restrict__ mapped, __half* __restrict__ y2h,
                       int n, int gT){
  int l = threadIdx.x & 15;
  if((int)blockIdx.x < gT){
    int row = blockIdx.x*16 + (threadIdx.x>>4);
    if(row>=n) return;
    f16x2 acc2[4];
    spmm_row16_h(rs, e1, h1h, row, l, acc2);
    float4 b0 = ((const float4*)b1)[2*l], bb1 = ((const float4*)b1)[2*l+1];
    union{ uint4 v; __half2 h2[4]; } o;
    o.h2[0] = __floats2half2_rn(tanhf((float)acc2[0].x+b0.x), tanhf((float)acc2[0].y+b0.y));
    o.h2[1] = __floats2half2_rn(tanhf((float)acc2[1].x+b0.z), tanhf((float)acc2[1].y+b0.w));
    o.h2[2] = __floats2half2_rn(tanhf((float)acc2[2].x+bb1.x), tanhf((float)acc2[2].y+bb1.y));
    o.h2[3] = __floats2half2_rn(tanhf((float)acc2[3].x+bb1.z), tanhf((float)acc2[3].y+bb1.w));
    ((uint4*)(y1h + (size_t)row*DD))[l] = o.v;
  } else {
    int row = (blockIdx.x-gT)*16 + (threadIdx.x>>4);
    if(row>=n) return;
    attn_row16(rs+(n+1), e2, s1, s2, mapped, y2h, row, l);
  }
}

// ================= spmm2 + final fused: y4 row -> l2norms -> output =================
__global__ void k_spmm_final(const int* __restrict__ rs, const int2* __restrict__ e1,
                             const __half* __restrict__ h, const float* __restrict__ bias,
                             const __half* __restrict__ y3, const float* __restrict__ x,
                             float* __restrict__ out, int n){
  int row = blockIdx.x*16 + (threadIdx.x>>4);
  if(row>=n) return;
  int l = threadIdx.x & 15;
  f16x2 acc2[4];
  spmm_row16_h(rs, e1, h, row, l, acc2);
  float4 b0 = ((const float4*)bias)[2*l], b1 = ((const float4*)bias)[2*l+1];
  float y4v[8];
  y4v[0]=tanhf((float)acc2[0].x+b0.x); y4v[1]=tanhf((float)acc2[0].y+b0.y);
  y4v[2]=tanhf((float)acc2[1].x+b0.z); y4v[3]=tanhf((float)acc2[1].y+b0.w);
  y4v[4]=tanhf((float)acc2[2].x+b1.x); y4v[5]=tanhf((float)acc2[2].y+b1.y);
  y4v[6]=tanhf((float)acc2[3].x+b1.z); y4v[7]=tanhf((float)acc2[3].y+b1.w);
  union{ uint4 v; __half2 h2[4]; } y3u;
  y3u.v = ((const uint4*)(y3 + (size_t)row*DD))[l];
  float y3v[8];
  #pragma unroll
  for(int q=0;q<4;++q){
    float2 f = __half22float2(y3u.h2[q]);
    y3v[2*q] = f.x; y3v[2*q+1] = f.y;
  }
  const float* xp = x + (size_t)row*DD + l*8;
  float4 xa = *(const float4*)xp, xb = *(const float4*)(xp+4);
  float xv[8] = {xa.x,xa.y,xa.z,xa.w,xb.x,xb.y,xb.z,xb.w};
  float sa=0.f, sb=0.f, sc=0.f;
  #pragma unroll
  for(int q=0;q<8;++q){ sa += y3v[q]*y3v[q]; sb += y4v[q]*y4v[q]; sc += xv[q]*xv[q]; }
  #pragma unroll
  for(int off=1; off<16; off<<=1){
    sa += __shfl_xor(sa, off, 64);
    sb += __shfl_xor(sb, off, 64);
    sc += __shfl_xor(sc, off, 64);
  }
  float ia = rsqrtf(fmaxf(sa, 1e-12f));
  float ib = rsqrtf(fmaxf(sb, 1e-12f));
  float ic = rsqrtf(fmaxf(sc, 1e-12f));
  float tot = sa*ia*ia + sb*ib*ib + sc*ic*ic;
  float f = rsqrtf(fmaxf(tot, 1e-12f));
  float fa = ia*f, fb = ib*f, fc = ic*f;
  float* o = out + (size_t)row*(3*DD);
  *(float4*)(o + l*8)     = make_float4(y3v[0]*fa, y3v[1]*fa, y3v[2]*fa, y3v[3]*fa);
  *(float4*)(o + l*8 + 4) = make_float4(y3v[4]*fa, y3v[5]*fa, y3v[6]*fa, y3v[7]*fa);
  *(float4*)(o + DD + l*8)     = make_float4(y4v[0]*fb, y4v[1]*fb, y4v[2]*fb, y4v[3]*fb);
  *(float4*)(o + DD + l*8 + 4) = make_float4(y4v[4]*fb, y4v[5]*fb, y4v[6]*fb, y4v[7]*fb);
  *(float4*)(o + 2*DD + l*8)     = make_float4(xv[0]*fc, xv[1]*fc, xv[2]*fc, xv[3]*fc);
  *(float4*)(o + 2*DD + l*8 + 4) = make_float4(xv[4]*fc, xv[5]*fc, xv[6]*fc, xv[7]*fc);
}

// ================= launch =================
extern "C" void kernel_launch(void* const* d_in, const int* in_sizes, int n_in,
                              void* d_out, int out_size, void* d_ws, size_t ws_size,
                              hipStream_t stream){
  const float* x   = (const float*)d_in[0];
  const int*   a1r = (const int*)d_in[1];
  const int*   a1c = (const int*)d_in[2];
  const float* a1v = (const float*)d_in[3];
  const int*   a2r = (const int*)d_in[4];
  const int*   a2c = (const int*)d_in[5];
  const float* w1  = (const float*)d_in[7];
  const float* b1  = (const float*)d_in[8];
  const float* watt= (const float*)d_in[9];
  const float* m1  = (const float*)d_in[10];
  const float* m2  = (const float*)d_in[11];
  const float* whw = (const float*)d_in[12];
  const float* w2  = (const float*)d_in[13];
  const float* b2  = (const float*)d_in[14];

  const int N = in_sizes[0]/DD;
  const int E = in_sizes[1];
  const float BN = (float)(1.0/sqrt(1.0+1e-3));
  const size_t NB = (size_t)N*DD;

  int tile = 8192, nt = (E+tile-1)/tile;
  while(nt > 256){ tile <<= 1; nt = (E+tile-1)/tile; }
  const int nbk = (N + (1<<BSH) - 1) >> BSH;

  // workspace layout (f16 activations; st1/st2 dedicated)
  f16* Bh = (f16*)d_ws;             // h1h -> h3h
  f16* Ch = Bh + NB;                // mapped -> y3h
  f16* Dh = Ch + NB;                // y1h
  f16* Eh = Dh + NB;                // y2h
  f16* wh = Eh + NB;                // 6*16384
  float* s1 = (float*)(wh + 6*16384);   // N
  float* s2 = s1 + N;               // N
  int*  rs  = (int*)(s2 + N);       // 2*(N+1)
  uintptr_t pa = ((uintptr_t)(rs + 2*(N+1)) + 15) & ~(uintptr_t)15;
  int2* e1  = (int2*)pa;            // E
  int*  e2  = (int*)(e1 + E);       // E
  uintptr_t pb = ((uintptr_t)(e2 + E) + 15) & ~(uintptr_t)15;
  int2* st1 = (int2*)pb;            // E (dedicated)
  int*  st2 = (int*)(st1 + E);      // E (dedicated)
  int*  hist = st2 + E;             // 2*nt*256
  int*  colsum = hist + (size_t)2*nt*256; // 512
  int*  base = colsum + 512;        // 2*257

  const int gT = (N+15)/16;
  const int gM = (N+63)/64;
  float* out = (float*)d_out;

  // ---- wprep + hist (merged) ----
  k_ph<<<6+nt,256,0,stream>>>(w1, watt, m1, m2, whw, w2, wh, a1r, a2r, hist, E, tile, nt);

  // ---- scans ----
  k_colscan<<<512,256,0,stream>>>(hist, colsum, nt);
  k_basescan<<<1,512,0,stream>>>(colsum, base);

  // ---- partition + x-GEMMs (merged): st1/st2, h1h(Bh), mapped(Ch), s1, s2 ----
  k_px<<<nt+gM,256,0,stream>>>(a1r,a1c,a1v, a2r,a2c, hist, base, st1, st2, E, tile, nt,
                               x, wh, Bh, Ch, s1, s2, BN, BN*BN, N);

  // ---- CSR finalize ----
  k_csr_bucket<<<2*nbk,256,0,stream>>>(st1, st2, base, e1, e2, rs, N, nbk);

  // ---- merged aggregation: y1h(Dh) + y2h(Eh) ----
  k_agg1<<<2*gT,256,0,stream>>>(rs, e1, (const __half*)Bh, b1, (__half*)Dh,
                                e2, s1, s2, (const __half*)Ch, (__half*)Eh, N, gT);

  // ---- highway + gcn2 GEMMs: y3h(Ch), h3h(Bh) ----
  k_hw2<<<gM,256,0,stream>>>(Eh, Dh, wh, Ch, Bh, BN, N);

  // ---- GCN2 aggregate + final fused ----
  k_spmm_final<<<gT,256,0,stream>>>(rs, e1, (const __half*)Bh, b2,
                                    (const __half*)Ch, x, out, N);
}